// Round 4
// baseline (770.321 us; speedup 1.0000x reference)
//
#include <hip/hip_runtime.h>
#include <hip/hip_bf16.h>
#include <math.h>

typedef unsigned short u16;
typedef float fx4 __attribute__((ext_vector_type(4)));
typedef __bf16 bx8 __attribute__((ext_vector_type(8)));

constexpr int BB  = 8;
constexpr int HH  = 256;
constexpr int LL  = 8192;
constexpr int NN  = 16;
constexpr int DTE = 512;
constexpr int SC  = 64;     // chunk length for the scan (W^SC used in carry scan)
constexpr int CHN = 128;    // number of chunks per row
constexpr int HN  = HH * NN;

constexpr size_t BHL = (size_t)BB * HH * LL;

constexpr int OFF_WR  = 0;
constexpr int OFF_WI  = HN;
constexpr int OFF_WSR = 2 * HN;
constexpr int OFF_WSI = 3 * HN;
constexpr int OFF_C0R = 4 * HN;
constexpr int OFF_C0I = 5 * HN;
constexpr int OFF_C1R = 6 * HN;
constexpr int OFF_C1I = 7 * HN;
constexpr int OFF_PT  = 8 * HN;

// PM (per-h scan matrices, u16 units): 6x 64x64 bf16
constexpr int PM_V2H = 0;
constexpr int PM_V2L = 4096;
constexpr int PM_TH  = 8192;
constexpr int PM_TL  = 12288;
constexpr int PM_CWH = 16384;
constexpr int PM_CWL = 20480;
constexpr int PM_STRIDE = 24576;

__device__ __forceinline__ float gelu_tanh(float x) {
    float x3 = x * x * x;
    float y = 1.5957691216057308f * x + 0.07135481627767453f * x3;
    return x / (1.0f + __expf(-y));
}
__device__ __forceinline__ float sigmoid_(float x) {
    return 1.0f / (1.0f + __expf(-x));
}
__device__ __forceinline__ __hip_bfloat16 f2b(float x) { return __float2bfloat16(x); }
__device__ __forceinline__ float b2f(__hip_bfloat16 x) { return __bfloat162float(x); }
__device__ __forceinline__ u16 f2us(float x) {
    __hip_bfloat16 b = __float2bfloat16(x);
    return *reinterpret_cast<u16*>(&b);
}
__device__ __forceinline__ float lo2f(unsigned v) { return __uint_as_float(v << 16); }
__device__ __forceinline__ float hi2f(unsigned v) { return __uint_as_float(v & 0xffff0000u); }
__device__ __forceinline__ unsigned pack2(float a, float b) {
    return (unsigned)f2us(a) | ((unsigned)f2us(b) << 16);
}

__global__ void setup_s4_params(const float* __restrict__ log_dt,
                                const float* __restrict__ A_re,
                                const float* __restrict__ A_im,
                                const float* __restrict__ C_re,
                                const float* __restrict__ C_im,
                                float* __restrict__ P) {
    int idx = blockIdx.x * blockDim.x + threadIdx.x;
    if (idx >= HN) return;
    int h = idx >> 4;
    double dt = exp((double)log_dt[h]);
    double Ar = (double)A_re[idx], Ai = (double)A_im[idx];
    double dr = Ar * dt, di = Ai * dt;
    double e1 = exp(dr);
    double wr = e1 * cos(di), wi = e1 * sin(di);
    double eS = exp(dr * SC);
    double wSr = eS * cos(di * SC), wSi = eS * sin(di * SC);
    double d2 = Ar * Ar + Ai * Ai;
    double nr = wr - 1.0, ni = wi;
    double rr = (nr * Ar + ni * Ai) / d2;
    double ri = (ni * Ar - nr * Ai) / d2;
    double c0r = (double)C_re[idx],        c0i = (double)C_im[idx];
    double c1r = (double)C_re[HN + idx],   c1i = (double)C_im[HN + idx];
    P[OFF_WR  + idx] = (float)wr;
    P[OFF_WI  + idx] = (float)wi;
    P[OFF_WSR + idx] = (float)wSr;
    P[OFF_WSI + idx] = (float)wSi;
    P[OFF_C0R + idx] = (float)(2.0 * (c0r * rr - c0i * ri));
    P[OFF_C0I + idx] = (float)(2.0 * (c0r * ri + c0i * rr));
    P[OFF_C1R + idx] = (float)(2.0 * (c1r * rr - c1i * ri));
    P[OFF_C1I + idx] = (float)(2.0 * (c1r * ri + c1i * rr));
}

// Per-h scan matrices: V2 (states x j), T (t x j Toeplitz, D on diag), CW (t x carry-state).
__global__ void setup_scan_mats(const float* __restrict__ P,
                                const float* __restrict__ Dp,
                                u16* __restrict__ PM) {
    const int h = blockIdx.x;
    const int t = threadIdx.x;   // 0..63
    __shared__ float Wr[65][17], Wi[65][17];
    __shared__ float KF[64], KB[64];
    __shared__ float c0r[16], c0i[16], c1r[16], c1i[16];
    if (t < 16) {
        c0r[t] = P[OFF_C0R + h * NN + t]; c0i[t] = P[OFF_C0I + h * NN + t];
        c1r[t] = P[OFF_C1R + h * NN + t]; c1i[t] = P[OFF_C1I + h * NN + t];
        double wr = (double)P[OFF_WR + h * NN + t], wi = (double)P[OFF_WI + h * NN + t];
        double pr = 1.0, pi = 0.0;
        for (int tau = 0; tau <= 64; ++tau) {
            Wr[tau][t] = (float)pr; Wi[tau][t] = (float)pi;
            double nr = pr * wr - pi * wi, ni = pr * wi + pi * wr;
            pr = nr; pi = ni;
        }
    }
    __syncthreads();
    {
        float kf = 0.f, kb = 0.f;
        #pragma unroll
        for (int n = 0; n < 16; ++n) {
            kf = fmaf(c0r[n], Wr[t][n], fmaf(-c0i[n], Wi[t][n], kf));
            kb = fmaf(c1r[n], Wr[t][n], fmaf(-c1i[n], Wi[t][n], kb));
        }
        KF[t] = kf; KB[t] = kb;
    }
    __syncthreads();
    u16* base = PM + (size_t)h * PM_STRIDE;
    {
        int n = (t & 31) >> 1, reim = t & 1;
        bool fwd = t < 32;
        for (int j = 0; j < 64; ++j) {
            int e = fwd ? (63 - j) : j;
            float v = reim ? Wi[e][n] : Wr[e][n];
            __hip_bfloat16 hb = f2b(v);
            base[PM_V2H + t * 64 + j] = *(u16*)&hb;
            base[PM_V2L + t * 64 + j] = f2us(v - b2f(hb));
        }
    }
    {
        float Dh = Dp[h];
        for (int j = 0; j < 64; ++j) {
            float v = (j < t) ? KF[t - j] : ((j == t) ? (KF[0] + Dh) : KB[j - t - 1]);
            __hip_bfloat16 hb = f2b(v);
            base[PM_TH + t * 64 + j] = *(u16*)&hb;
            base[PM_TL + t * 64 + j] = f2us(v - b2f(hb));
        }
    }
    {
        #pragma unroll
        for (int n = 0; n < 16; ++n) {
            float Rw = Wr[t + 1][n], Iw = Wi[t + 1][n];
            float af = fmaf(c0r[n], Rw, -c0i[n] * Iw);
            float bf = -fmaf(c0r[n], Iw, c0i[n] * Rw);
            float Rb = Wr[63 - t][n], Ib = Wi[63 - t][n];
            float ab = fmaf(c1r[n], Rb, -c1i[n] * Ib);
            float bb = -fmaf(c1r[n], Ib, c1i[n] * Rb);
            float vals[4] = {af, bf, ab, bb};
            int cols[4] = {2 * n, 2 * n + 1, 32 + 2 * n, 32 + 2 * n + 1};
            #pragma unroll
            for (int q = 0; q < 4; ++q) {
                __hip_bfloat16 hb = f2b(vals[q]);
                base[PM_CWH + t * 64 + cols[q]] = *(u16*)&hb;
                base[PM_CWL + t * 64 + cols[q]] = f2us(vals[q] - b2f(hb));
            }
        }
    }
}

__global__ void part_t_kernel(const float* __restrict__ emb,
                              const float* __restrict__ w,
                              const float* __restrict__ bias,
                              float* __restrict__ P) {
    int idx = blockIdx.x * blockDim.x + threadIdx.x;
    if (idx >= BB * HH) return;
    int b = idx / HH, h = idx % HH;
    float s = bias[h];
    const float* er = emb + (size_t)b * DTE;
    const float* wr = w + (size_t)h * DTE;
    for (int e = 0; e < DTE; ++e) s = fmaf(er[e], wr[e], s);
    P[OFF_PT + idx] = s;
}

__global__ void convert_w_kernel(const float* __restrict__ src, u16* __restrict__ dst, int n) {
    int i = blockIdx.x * 256 + threadIdx.x;
    if (i < n) dst[i] = f2us(src[i]);
}

__global__ void convert_w_split(const float* __restrict__ src,
                                u16* __restrict__ hi, u16* __restrict__ lo, int n) {
    int i = blockIdx.x * 256 + threadIdx.x;
    if (i < n) {
        float v = src[i];
        __hip_bfloat16 hb = f2b(v);
        hi[i] = *reinterpret_cast<u16*>(&hb);
        lo[i] = f2us(v - b2f(hb));
    }
}

__global__ void tln_kernel(const float* __restrict__ in, float* __restrict__ out,
                           const float* __restrict__ mptr, const float* __restrict__ sptr,
                           const float* __restrict__ part_t) {
    int b = blockIdx.y;
    int l0 = blockIdx.x * 64;
    int t = threadIdx.x;
    int q = t >> 6, li = t & 63;
    const float* base = in + (size_t)b * HH * LL + l0 + li;
    float sum = 0.f, sq = 0.f;
    for (int i = 0; i < 64; ++i) {
        float v = base[(size_t)(q * 64 + i) * LL];
        sum += v; sq = fmaf(v, v, sq);
    }
    __shared__ float rs[4][64], rq[4][64], meanS[64], scaleS[64];
    rs[q][li] = sum; rq[q][li] = sq;
    __syncthreads();
    if (q == 0) {
        float s  = rs[0][li] + rs[1][li] + rs[2][li] + rs[3][li];
        float s2 = rq[0][li] + rq[1][li] + rq[2][li] + rq[3][li];
        float mean = s * (1.f / 256.f);
        float var  = fmaxf(s2 * (1.f / 256.f) - mean * mean, 0.f);
        meanS[li]  = mean;
        scaleS[li] = sptr[0] / sqrtf(var);
    }
    __syncthreads();
    float mean = meanS[li], scale = scaleS[li], m = mptr[0];
    float* ob = out + (size_t)b * HH * LL + l0 + li;
    for (int i = 0; i < 64; ++i) {
        int h = q * 64 + i;
        float v = base[(size_t)h * LL];
        float y = scale * (v - mean + m) + part_t[b * HH + h];
        ob[(size_t)h * LL] = y;
    }
}

__global__ void tln2t_kernel(const float* __restrict__ in, u16* __restrict__ outT,
                             const float* __restrict__ mptr, const float* __restrict__ sptr) {
    int b = blockIdx.y;
    int l0 = blockIdx.x * 64;
    int t = threadIdx.x;
    int q = t >> 6, li = t & 63;
    const float* base = in + (size_t)b * HH * LL + l0 + li;
    float sum = 0.f, sq = 0.f;
    for (int i = 0; i < 64; ++i) {
        float v = base[(size_t)(q * 64 + i) * LL];
        sum += v; sq = fmaf(v, v, sq);
    }
    __shared__ float rs[4][64], rq[4][64], meanS[64], scaleS[64];
    __shared__ u16 TT[64 * 262];
    rs[q][li] = sum; rq[q][li] = sq;
    __syncthreads();
    if (q == 0) {
        float s  = rs[0][li] + rs[1][li] + rs[2][li] + rs[3][li];
        float s2 = rq[0][li] + rq[1][li] + rq[2][li] + rq[3][li];
        float mean = s * (1.f / 256.f);
        float var  = fmaxf(s2 * (1.f / 256.f) - mean * mean, 0.f);
        meanS[li]  = mean;
        scaleS[li] = sptr[0] / sqrtf(var);
    }
    __syncthreads();
    float mean = meanS[li], scale = scaleS[li], m = mptr[0];
    for (int i = 0; i < 64; ++i) {
        int h = q * 64 + i;
        float v = base[(size_t)h * LL];
        TT[li * 262 + h] = f2us(scale * (v - mean + m));
    }
    __syncthreads();
    #pragma unroll
    for (int i = 0; i < 32; ++i) {
        int idx = t + i * 256;
        int c = idx & 127, l = idx >> 7;
        unsigned int v = *(const unsigned int*)&TT[l * 262 + 2 * c];
        *(unsigned int*)&outT[((size_t)b * LL + l0 + l) * 256 + 2 * c] = v;
    }
}

// ---- MFMA scan (unchanged from R2)
constexpr int UPAD = 136;
constexpr int SPAD = 72;

__global__ __launch_bounds__(256, 3) void scan_mfma(
    const float* __restrict__ uIn, const float* __restrict__ P,
    const u16* __restrict__ PM, float* __restrict__ ys)
{
    __shared__ __align__(16) u16 U[128 * UPAD];
    __shared__ __align__(16) u16 SES[128 * SPAD];

    const int bh  = blockIdx.x;
    const int h   = bh & (HH - 1);
    const int tid = threadIdx.x;
    const int lane = tid & 63;
    const int wq   = tid >> 6;
    const u16* pm = PM + (size_t)h * PM_STRIDE;
    const float* urow = uIn + (size_t)bh * LL;
    float* yrow = ys + (size_t)bh * LL;

    {
        const float4* u4 = (const float4*)urow;
        #pragma unroll
        for (int i = 0; i < 8; ++i) {
            int e4 = tid + i * 256;
            float4 v = u4[e4];
            int g = e4 << 2, c = g >> 6, j = g & 63;
            u16 hi4[4], lo4[4];
            #pragma unroll
            for (int q = 0; q < 4; ++q) {
                float f = (&v.x)[q];
                __hip_bfloat16 hb = f2b(f);
                hi4[q] = *(u16*)&hb;
                lo4[q] = f2us(f - b2f(hb));
            }
            *(ushort4*)&U[c * UPAD + j]      = *(ushort4*)hi4;
            *(ushort4*)&U[c * UPAD + 64 + j] = *(ushort4*)lo4;
        }
    }
    __syncthreads();

    const int cb    = wq * 32 + (lane & 15);
    const int kfrag = ((lane >> 4) & 3) * 8;
    const int arow_lo = lane & 15;

    bx8 ubh[2][2], ubl[2][2];
    #pragma unroll
    for (int nt = 0; nt < 2; ++nt) {
        int c = cb + nt * 16;
        #pragma unroll
        for (int ks = 0; ks < 2; ++ks) {
            ubh[nt][ks] = *(const bx8*)&U[c * UPAD + ks * 32 + kfrag];
            ubl[nt][ks] = *(const bx8*)&U[c * UPAD + 64 + ks * 32 + kfrag];
        }
    }

    {
        fx4 acc[4][2];
        #pragma unroll
        for (int mt = 0; mt < 4; ++mt)
            #pragma unroll
            for (int nt = 0; nt < 2; ++nt) { fx4 z = {0.f,0.f,0.f,0.f}; acc[mt][nt] = z; }
        #pragma unroll
        for (int mt = 0; mt < 4; ++mt) {
            #pragma unroll
            for (int ks = 0; ks < 2; ++ks) {
                int ao = (mt * 16 + arow_lo) * 64 + ks * 32 + kfrag;
                bx8 vh = *(const bx8*)&pm[PM_V2H + ao];
                bx8 vl = *(const bx8*)&pm[PM_V2L + ao];
                #pragma unroll
                for (int nt = 0; nt < 2; ++nt) {
                    acc[mt][nt] = __builtin_amdgcn_mfma_f32_16x16x32_bf16(vh, ubh[nt][ks], acc[mt][nt], 0, 0, 0);
                    acc[mt][nt] = __builtin_amdgcn_mfma_f32_16x16x32_bf16(vh, ubl[nt][ks], acc[mt][nt], 0, 0, 0);
                    acc[mt][nt] = __builtin_amdgcn_mfma_f32_16x16x32_bf16(vl, ubh[nt][ks], acc[mt][nt], 0, 0, 0);
                }
            }
        }
        #pragma unroll
        for (int mt = 0; mt < 4; ++mt)
            #pragma unroll
            for (int nt = 0; nt < 2; ++nt) {
                int c = cb + nt * 16;
                int row = mt * 16 + (lane >> 4) * 4;
                #pragma unroll
                for (int r = 0; r < 4; ++r)
                    SES[c * SPAD + row + r] = f2us(acc[mt][nt][r]);
            }
    }
    __syncthreads();

    if (tid < 32) {
        const int d3 = tid >> 4, n = tid & 15;
        float wSr = P[OFF_WSR + h * NN + n], wSi = P[OFF_WSI + h * NN + n];
        const int kk = d3 * 32 + 2 * n;
        float cr = 0.f, ci = 0.f;
        if (d3 == 0) {
            for (int q = 0; q < CHN; ++q) {
                unsigned* p = (unsigned*)&SES[q * SPAD + kk];
                unsigned pv = *p;
                float fr = lo2f(pv), fi = hi2f(pv);
                *p = pack2(cr, ci);
                float nr2 = fmaf(wSr, cr, fmaf(-wSi, ci, fr));
                float ni2 = fmaf(wSr, ci, fmaf(wSi, cr, fi));
                cr = nr2; ci = ni2;
            }
        } else {
            for (int q = CHN - 1; q >= 0; --q) {
                unsigned* p = (unsigned*)&SES[q * SPAD + kk];
                unsigned pv = *p;
                float fr = lo2f(pv), fi = hi2f(pv);
                *p = pack2(cr, ci);
                float nr2 = fmaf(wSr, cr, fmaf(-wSi, ci, fr));
                float ni2 = fmaf(wSr, ci, fmaf(wSi, cr, fi));
                cr = nr2; ci = ni2;
            }
        }
    }
    __syncthreads();

    {
        bx8 sb[2][2];
        #pragma unroll
        for (int nt = 0; nt < 2; ++nt) {
            int c = cb + nt * 16;
            #pragma unroll
            for (int ks = 0; ks < 2; ++ks)
                sb[nt][ks] = *(const bx8*)&SES[c * SPAD + ks * 32 + kfrag];
        }
        fx4 acc[4][2];
        #pragma unroll
        for (int mt = 0; mt < 4; ++mt)
            #pragma unroll
            for (int nt = 0; nt < 2; ++nt) { fx4 z = {0.f,0.f,0.f,0.f}; acc[mt][nt] = z; }
        #pragma unroll
        for (int mt = 0; mt < 4; ++mt) {
            #pragma unroll
            for (int ks = 0; ks < 2; ++ks) {
                int ao = (mt * 16 + arow_lo) * 64 + ks * 32 + kfrag;
                bx8 th = *(const bx8*)&pm[PM_TH + ao];
                bx8 tl = *(const bx8*)&pm[PM_TL + ao];
                bx8 ch = *(const bx8*)&pm[PM_CWH + ao];
                bx8 cl = *(const bx8*)&pm[PM_CWL + ao];
                #pragma unroll
                for (int nt = 0; nt < 2; ++nt) {
                    acc[mt][nt] = __builtin_amdgcn_mfma_f32_16x16x32_bf16(th, ubh[nt][ks], acc[mt][nt], 0, 0, 0);
                    acc[mt][nt] = __builtin_amdgcn_mfma_f32_16x16x32_bf16(th, ubl[nt][ks], acc[mt][nt], 0, 0, 0);
                    acc[mt][nt] = __builtin_amdgcn_mfma_f32_16x16x32_bf16(tl, ubh[nt][ks], acc[mt][nt], 0, 0, 0);
                    acc[mt][nt] = __builtin_amdgcn_mfma_f32_16x16x32_bf16(ch, sb[nt][ks], acc[mt][nt], 0, 0, 0);
                    acc[mt][nt] = __builtin_amdgcn_mfma_f32_16x16x32_bf16(cl, sb[nt][ks], acc[mt][nt], 0, 0, 0);
                }
            }
        }
        #pragma unroll
        for (int mt = 0; mt < 4; ++mt)
            #pragma unroll
            for (int nt = 0; nt < 2; ++nt) {
                int c = cb + nt * 16;
                float4 ov;
                #pragma unroll
                for (int r = 0; r < 4; ++r)
                    (&ov.x)[r] = gelu_tanh(acc[mt][nt][r]);
                *(float4*)&yrow[c * 64 + mt * 16 + (lane >> 4) * 4] = ov;
            }
    }
}

// ---- GLU output projection via split-bf16 MFMA, K-tile 32, reg-prefetch pipeline.
__global__ __launch_bounds__(256, 3) void gemm_glu_mfma(
    const u16* __restrict__ Whi, const u16* __restrict__ Wlo,
    const float* __restrict__ Y, const float* __restrict__ bias,
    const float* __restrict__ xres, float* __restrict__ out)
{
    __shared__ __align__(16) char smem[33792];
    u16* Ah = (u16*)smem;           // [8 mtile][64 lane][8] u16 = 8192 B
    u16* Al = Ah + 4096;
    u16* Bh = Al + 4096;
    u16* Bl = Bh + 4096;

    const int tid  = threadIdx.x;
    const int lane = tid & 63;
    const int wv   = tid >> 6;
    const int wrh  = wv & 1;      // m-half: 0 -> z0 rows, 1 -> z1 rows
    const int wch  = wv >> 1;     // n-half: l offset wch*64
    const int bz   = blockIdx.z;
    const int l0   = blockIdx.x * 128;
    const int c0   = blockIdx.y * 64;

    fx4 acc[4][4];
    #pragma unroll
    for (int i = 0; i < 4; ++i)
        #pragma unroll
        for (int j = 0; j < 4; ++j) {
            fx4 z = {0.f, 0.f, 0.f, 0.f};
            acc[i][j] = z;
        }

    // staging maps
    const int am   = tid & 127;                     // A row 0..127
    const int aob  = (tid >> 7) * 2;                // A octet base
    const int aorow = (am < 64) ? (c0 + am) : (c0 + 256 + (am - 64));
    const int aldsbase = (am >> 4) * 64 + (am & 15);

    const int blc  = tid & 127;                     // B l 0..127
    const int bob  = (tid >> 7) * 2;                // B octet base
    const int bldsbase = (blc >> 4) * 64 + (blc & 15);

    const float* Yb = Y + (size_t)bz * HH * LL + l0 + blc;

    int4 rAh[2], rAl[2];
    float rB[16];

    #pragma unroll 1
    for (int kt = 0; kt < 8; ++kt) {
        if (kt == 0) {
            // prologue load
            #pragma unroll
            for (int o = 0; o < 2; ++o) {
                int k = (aob + o) * 8;
                rAh[o] = *(const int4*)&Whi[(size_t)aorow * 256 + k];
                rAl[o] = *(const int4*)&Wlo[(size_t)aorow * 256 + k];
            }
            #pragma unroll
            for (int o = 0; o < 2; ++o) {
                int kb = (bob + o) * 8;
                #pragma unroll
                for (int j = 0; j < 8; ++j)
                    rB[o * 8 + j] = Yb[(size_t)(kb + j) * LL];
            }
        }
        // store regs -> LDS
        #pragma unroll
        for (int o = 0; o < 2; ++o) {
            int idx = (aldsbase + (aob + o) * 16) * 8;
            *(int4*)&Ah[idx] = rAh[o];
            *(int4*)&Al[idx] = rAl[o];
        }
        #pragma unroll
        for (int o = 0; o < 2; ++o) {
            u16 h8[8], l8[8];
            #pragma unroll
            for (int j = 0; j < 8; ++j) {
                float v = rB[o * 8 + j];
                __hip_bfloat16 hb = f2b(v);
                h8[j] = *(u16*)&hb;
                l8[j] = f2us(v - b2f(hb));
            }
            int idx = (bldsbase + (bob + o) * 16) * 8;
            *(int4*)&Bh[idx] = *(const int4*)h8;
            *(int4*)&Bl[idx] = *(const int4*)l8;
        }
        __syncthreads();
        // issue next tile's loads (fly under MFMA)
        if (kt < 7) {
            int k0 = (kt + 1) * 32;
            #pragma unroll
            for (int o = 0; o < 2; ++o) {
                int k = k0 + (aob + o) * 8;
                rAh[o] = *(const int4*)&Whi[(size_t)aorow * 256 + k];
                rAl[o] = *(const int4*)&Wlo[(size_t)aorow * 256 + k];
            }
            #pragma unroll
            for (int o = 0; o < 2; ++o) {
                int kb = k0 + (bob + o) * 8;
                #pragma unroll
                for (int j = 0; j < 8; ++j)
                    rB[o * 8 + j] = Yb[(size_t)(kb + j) * LL];
            }
        }
        // MFMA on current LDS tile
        {
            bx8 bh[4], blv[4];
            #pragma unroll
            for (int nt = 0; nt < 4; ++nt) {
                int base = ((wch * 4 + nt) * 64 + lane) * 8;
                bh[nt]  = *(const bx8*)&Bh[base];
                blv[nt] = *(const bx8*)&Bl[base];
            }
            #pragma unroll
            for (int mt = 0; mt < 4; ++mt) {
                int base = ((wrh * 4 + mt) * 64 + lane) * 8;
                bx8 ah = *(const bx8*)&Ah[base];
                bx8 al = *(const bx8*)&Al[base];
                #pragma unroll
                for (int nt = 0; nt < 4; ++nt) {
                    acc[mt][nt] = __builtin_amdgcn_mfma_f32_16x16x32_bf16(ah, bh[nt], acc[mt][nt], 0, 0, 0);
                    acc[mt][nt] = __builtin_amdgcn_mfma_f32_16x16x32_bf16(ah, blv[nt], acc[mt][nt], 0, 0, 0);
                    acc[mt][nt] = __builtin_amdgcn_mfma_f32_16x16x32_bf16(al, bh[nt], acc[mt][nt], 0, 0, 0);
                }
            }
        }
        __syncthreads();
    }

    // epilogue: z1 waves publish to LDS, z0 waves apply GLU + residual
    float* zbuf = (float*)smem;   // [2][64][65] floats = 33280 B
    if (wrh == 1) {
        #pragma unroll
        for (int mt = 0; mt < 4; ++mt) {
            int mloc = mt * 16 + (lane >> 4) * 4;
            float b1v[4];
            #pragma unroll
            for (int r = 0; r < 4; ++r) b1v[r] = bias[c0 + 256 + mloc + r];
            #pragma unroll
            for (int nt = 0; nt < 4; ++nt) {
                int nloc = nt * 16 + (lane & 15);
                #pragma unroll
                for (int r = 0; r < 4; ++r)
                    zbuf[wch * 4160 + (mloc + r) * 65 + nloc] = acc[mt][nt][r] + b1v[r];
            }
        }
    }
    __syncthreads();
    if (wrh == 0) {
        #pragma unroll
        for (int mt = 0; mt < 4; ++mt) {
            int mloc = mt * 16 + (lane >> 4) * 4;
            float b0v[4];
            #pragma unroll
            for (int r = 0; r < 4; ++r) b0v[r] = bias[c0 + mloc + r];
            #pragma unroll
            for (int nt = 0; nt < 4; ++nt) {
                int nloc = nt * 16 + (lane & 15);
                int l = l0 + wch * 64 + nloc;
                #pragma unroll
                for (int r = 0; r < 4; ++r) {
                    float z1 = zbuf[wch * 4160 + (mloc + r) * 65 + nloc];
                    float z0 = acc[mt][nt][r] + b0v[r];
                    size_t ga = ((size_t)bz * HH + c0 + mloc + r) * LL + l;
                    out[ga] = z0 * sigmoid_(z1) + xres[ga];
                }
            }
        }
    }
}

template<int MODE, int WLD>
__global__ __launch_bounds__(256, 3) void gemm_mfma(
    const u16* __restrict__ Aw, const u16* __restrict__ Bm,
    const float* bias, const float* resid, void* outv)
{
    __shared__ __align__(16) char smem[33792];
    u16*   Alds = (u16*)smem;
    u16*   Blds = (u16*)(smem + 16384);
    float* Eps  = (float*)smem;
    u16*   TT   = (u16*)smem;

    const int tid  = threadIdx.x;
    const int lane = tid & 63;
    const int wv   = tid >> 6;
    const int wr   = wv >> 1, wc = wv & 1;
    const int bz   = blockIdx.z;
    const int l0   = blockIdx.x * 128;
    const int mbase = blockIdx.y * 128;

    fx4 acc[4][4];
    #pragma unroll
    for (int i = 0; i < 4; ++i)
        #pragma unroll
        for (int j = 0; j < 4; ++j) {
            fx4 z = {0.f, 0.f, 0.f, 0.f};
            acc[i][j] = z;
        }

    const size_t brow0 = (size_t)bz * LL;
    int4 rA[4], rB[4];

    #pragma unroll 1
    for (int kt = 0; kt < 4; ++kt) {
        if (kt == 0) {
            #pragma unroll
            for (int i = 0; i < 4; ++i) {
                int f = tid + i * 256;
                int mm = f & 15, kg = (f >> 4) & 3, m16 = (f >> 6) & 7, ks = f >> 9;
                int k = ks * 32 + kg * 8;
                rA[i] = *(const int4*)(Aw + (size_t)(mbase + m16 * 16 + mm) * WLD + k);
                rB[i] = *(const int4*)(Bm + (brow0 + l0 + m16 * 16 + mm) * 256 + k);
            }
        }
        #pragma unroll
        for (int i = 0; i < 4; ++i) {
            int f = tid + i * 256;
            *(int4*)&Alds[f * 8] = rA[i];
            *(int4*)&Blds[f * 8] = rB[i];
        }
        __syncthreads();
        if (kt < 3) {
            int k0 = (kt + 1) * 64;
            #pragma unroll
            for (int i = 0; i < 4; ++i) {
                int f = tid + i * 256;
                int mm = f & 15, kg = (f >> 4) & 3, m16 = (f >> 6) & 7, ks = f >> 9;
                int k = k0 + ks * 32 + kg * 8;
                rA[i] = *(const int4*)(Aw + (size_t)(mbase + m16 * 16 + mm) * WLD + k);
                rB[i] = *(const int4*)(Bm + (brow0 + l0 + m16 * 16 + mm) * 256 + k);
            }
        }
        #pragma unroll
        for (int ks = 0; ks < 2; ++ks) {
            bx8 av[4], bv[4];
            #pragma unroll
            for (int mt = 0; mt < 4; ++mt)
                av[mt] = *(const bx8*)&Alds[(ks * 512 + (wr * 4 + mt) * 64 + lane) * 8];
            #pragma unroll
            for (int nt = 0; nt < 4; ++nt)
                bv[nt] = *(const bx8*)&Blds[(ks * 512 + (wc * 4 + nt) * 64 + lane) * 8];
            #pragma unroll
            for (int mt = 0; mt < 4; ++mt)
                #pragma unroll
                for (int nt = 0; nt < 4; ++nt)
                    acc[mt][nt] = __builtin_amdgcn_mfma_f32_16x16x32_bf16(
                        av[mt], bv[nt], acc[mt][nt], 0, 0, 0);
        }
        __syncthreads();
    }

    if (MODE == 1) {
        u16* hT = (u16*)outv;
        #pragma unroll
        for (int p = 0; p < 2; ++p) {
            if (p) __syncthreads();
            if (wc == p) {
                #pragma unroll
                for (int mt = 0; mt < 4; ++mt) {
                    int mb = wr * 64 + mt * 16 + (lane >> 4) * 4;
                    float bvv[4];
                    #pragma unroll
                    for (int r = 0; r < 4; ++r) bvv[r] = bias[mbase + mb + r];
                    #pragma unroll
                    for (int nt = 0; nt < 4; ++nt) {
                        int n = nt * 16 + (lane & 15);
                        u16 pk[4];
                        #pragma unroll
                        for (int r = 0; r < 4; ++r)
                            pk[r] = f2us(gelu_tanh(acc[mt][nt][r] + bvv[r]));
                        *(ushort4*)&TT[n * 136 + mb] = *(const ushort4*)pk;
                    }
                }
            }
            __syncthreads();
            #pragma unroll
            for (int i = 0; i < 4; ++i) {
                int idx = tid + i * 256;
                int l = idx >> 4, c = idx & 15;
                int4 v = *(const int4*)&TT[l * 136 + c * 8];
                *(int4*)&hT[((size_t)bz * LL + l0 + p * 64 + l) * 256 + mbase + c * 8] = v;
            }
        }
    } else {
        float* outp = (float*)outv;
        #pragma unroll
        for (int p = 0; p < 2; ++p) {
            if (p) __syncthreads();
            if (wc == p) {
                #pragma unroll
                for (int mt = 0; mt < 4; ++mt)
                    #pragma unroll
                    for (int nt = 0; nt < 4; ++nt) {
                        int m = wr * 64 + mt * 16 + (lane >> 4) * 4;
                        int n = nt * 16 + (lane & 15);
                        #pragma unroll
                        for (int r = 0; r < 4; ++r)
                            Eps[(m + r) * 66 + n] = acc[mt][nt][r];
                    }
            }
            __syncthreads();
            #pragma unroll
            for (int i = 0; i < 8; ++i) {
                int idx = tid + i * 256;
                int r = idx >> 4, lq = idx & 15;
                float bv = bias ? bias[mbase + r] : 0.f;
                size_t ga = ((size_t)bz * HH + mbase + r) * LL + l0 + p * 64 + lq * 4;
                float4 rv = *(const float4*)&resid[ga];
                float4 ov;
                #pragma unroll
                for (int j = 0; j < 4; ++j)
                    (&ov.x)[j] = Eps[r * 66 + lq * 4 + j] + bv + (&rv.x)[j];
                *(float4*)&outp[ga] = ov;
            }
        }
    }
}

extern "C" void kernel_launch(void* const* d_in, const int* in_sizes, int n_in,
                              void* d_out, int out_size, void* d_ws, size_t ws_size,
                              hipStream_t stream) {
    (void)in_sizes; (void)n_in; (void)out_size; (void)ws_size;
    const float* x      = (const float*)d_in[0];
    const float* emb    = (const float*)d_in[1];
    const float* fc_t_w = (const float*)d_in[2];
    const float* fc_t_b = (const float*)d_in[3];
    const float* log_dt = (const float*)d_in[4];
    const float* A_re   = (const float*)d_in[5];
    const float* A_im   = (const float*)d_in[6];
    const float* C_re   = (const float*)d_in[7];
    const float* C_im   = (const float*)d_in[8];
    const float* Dp     = (const float*)d_in[9];
    const float* out_w  = (const float*)d_in[10];
    const float* out_b  = (const float*)d_in[11];
    const float* n1_m   = (const float*)d_in[12];
    const float* n1_s   = (const float*)d_in[13];
    const float* n2_m   = (const float*)d_in[14];
    const float* n2_s   = (const float*)d_in[15];
    const float* ff_w1  = (const float*)d_in[16];
    const float* ff_b1  = (const float*)d_in[17];
    const float* ff_w2  = (const float*)d_in[18];
    const float* ff_b2  = (const float*)d_in[19];
    float* outp = (float*)d_out;

    float* wsf  = (float*)d_ws;
    float* u    = wsf;
    u16*   t2T  = (u16*)wsf;
    u16*   hT   = (u16*)(wsf + BHL);
    u16*   PM   = (u16*)(wsf + BHL + BHL / 2);      // 256*24576 u16 = 12 MB
    constexpr size_t WPOFF = 2 * BHL - 524288;
    u16*   W1c  = (u16*)(wsf + WPOFF);              // 512*256 bf16
    u16*   W2c  = W1c + 131072;                     // 256*512 bf16
    u16*   WOh  = W2c + 131072;                     // out_w hi 512*256 bf16
    u16*   WOl  = WOh + 131072;                     // out_w lo 512*256 bf16
    float* P    = wsf + WPOFF + 262144;             // 34,816 floats

    setup_s4_params<<<16, 256, 0, stream>>>(log_dt, A_re, A_im, C_re, C_im, P);
    part_t_kernel<<<8, 256, 0, stream>>>(emb, fc_t_w, fc_t_b, P);
    setup_scan_mats<<<HH, 64, 0, stream>>>(P, Dp, PM);
    convert_w_kernel<<<512, 256, 0, stream>>>(ff_w1, W1c, 512 * 256);
    convert_w_kernel<<<512, 256, 0, stream>>>(ff_w2, W2c, 256 * 512);
    convert_w_split<<<512, 256, 0, stream>>>(out_w, WOh, WOl, 512 * 256);

    // u = TLN1(x) + part_t
    tln_kernel<<<dim3(LL / 64, BB), 256, 0, stream>>>(x, u, n1_m, n1_s, P + OFF_PT);

    // ys4 = gelu(S4_bidir(u) + u*D), in place over u  (MFMA formulation)
    scan_mfma<<<BB * HH, 256, 0, stream>>>(u, P, PM, u);

    // res = x + GLU(out_w @ ys4 + out_b) -> d_out
    gemm_glu_mfma<<<dim3(LL / 128, 4, BB), 256, 0, stream>>>(WOh, WOl, u, out_b, x, outp);

    // t2T = TLN2(res) transposed bf16
    tln2t_kernel<<<dim3(LL / 64, BB), 256, 0, stream>>>(outp, t2T, n2_m, n2_s);

    // FF in two hidden halves; hT half = 32 MB in region B
    gemm_mfma<1, 256><<<dim3(LL / 128, 2, BB), 256, 0, stream>>>(W1c, t2T, ff_b1, nullptr, hT);
    gemm_mfma<2, 512><<<dim3(LL / 128, 2, BB), 256, 0, stream>>>(W2c, hT, ff_b2, outp, outp);
    gemm_mfma<1, 256><<<dim3(LL / 128, 2, BB), 256, 0, stream>>>(W1c + 65536, t2T, ff_b1 + 256, nullptr, hT);
    gemm_mfma<2, 512><<<dim3(LL / 128, 2, BB), 256, 0, stream>>>(W2c + 256, hT, nullptr, outp, outp);
}

// Round 5
// 513.783 us; speedup vs baseline: 1.4993x; 1.4993x over previous
//
#include <hip/hip_runtime.h>
#include <hip/hip_bf16.h>
#include <math.h>

typedef unsigned short u16;
typedef float fx4 __attribute__((ext_vector_type(4)));
typedef __bf16 bx8 __attribute__((ext_vector_type(8)));

constexpr int BB  = 8;
constexpr int HH  = 256;
constexpr int LL  = 8192;
constexpr int NN  = 16;
constexpr int DTE = 512;
constexpr int SC  = 64;     // chunk length for the scan (W^SC used in carry scan)
constexpr int CHN = 128;    // number of chunks per row
constexpr int HN  = HH * NN;

constexpr size_t BHL = (size_t)BB * HH * LL;

constexpr int OFF_WR  = 0;
constexpr int OFF_WI  = HN;
constexpr int OFF_WSR = 2 * HN;
constexpr int OFF_WSI = 3 * HN;
constexpr int OFF_C0R = 4 * HN;
constexpr int OFF_C0I = 5 * HN;
constexpr int OFF_C1R = 6 * HN;
constexpr int OFF_C1I = 7 * HN;
constexpr int OFF_PT  = 8 * HN;

// PM (per-h scan matrices, u16 units): 6x 64x64 bf16
constexpr int PM_V2H = 0;
constexpr int PM_V2L = 4096;
constexpr int PM_TH  = 8192;
constexpr int PM_TL  = 12288;
constexpr int PM_CWH = 16384;
constexpr int PM_CWL = 20480;
constexpr int PM_STRIDE = 24576;

__device__ __forceinline__ float gelu_tanh(float x) {
    float x3 = x * x * x;
    float y = 1.5957691216057308f * x + 0.07135481627767453f * x3;
    return x / (1.0f + __expf(-y));
}
__device__ __forceinline__ float sigmoid_(float x) {
    return 1.0f / (1.0f + __expf(-x));
}
__device__ __forceinline__ __hip_bfloat16 f2b(float x) { return __float2bfloat16(x); }
__device__ __forceinline__ float b2f(__hip_bfloat16 x) { return __bfloat162float(x); }
__device__ __forceinline__ u16 f2us(float x) {
    __hip_bfloat16 b = __float2bfloat16(x);
    return *reinterpret_cast<u16*>(&b);
}
__device__ __forceinline__ float lo2f(unsigned v) { return __uint_as_float(v << 16); }
__device__ __forceinline__ float hi2f(unsigned v) { return __uint_as_float(v & 0xffff0000u); }
__device__ __forceinline__ unsigned pack2(float a, float b) {
    return (unsigned)f2us(a) | ((unsigned)f2us(b) << 16);
}

__global__ void setup_s4_params(const float* __restrict__ log_dt,
                                const float* __restrict__ A_re,
                                const float* __restrict__ A_im,
                                const float* __restrict__ C_re,
                                const float* __restrict__ C_im,
                                float* __restrict__ P) {
    int idx = blockIdx.x * blockDim.x + threadIdx.x;
    if (idx >= HN) return;
    int h = idx >> 4;
    double dt = exp((double)log_dt[h]);
    double Ar = (double)A_re[idx], Ai = (double)A_im[idx];
    double dr = Ar * dt, di = Ai * dt;
    double e1 = exp(dr);
    double wr = e1 * cos(di), wi = e1 * sin(di);
    double eS = exp(dr * SC);
    double wSr = eS * cos(di * SC), wSi = eS * sin(di * SC);
    double d2 = Ar * Ar + Ai * Ai;
    double nr = wr - 1.0, ni = wi;
    double rr = (nr * Ar + ni * Ai) / d2;
    double ri = (ni * Ar - nr * Ai) / d2;
    double c0r = (double)C_re[idx],        c0i = (double)C_im[idx];
    double c1r = (double)C_re[HN + idx],   c1i = (double)C_im[HN + idx];
    P[OFF_WR  + idx] = (float)wr;
    P[OFF_WI  + idx] = (float)wi;
    P[OFF_WSR + idx] = (float)wSr;
    P[OFF_WSI + idx] = (float)wSi;
    P[OFF_C0R + idx] = (float)(2.0 * (c0r * rr - c0i * ri));
    P[OFF_C0I + idx] = (float)(2.0 * (c0r * ri + c0i * rr));
    P[OFF_C1R + idx] = (float)(2.0 * (c1r * rr - c1i * ri));
    P[OFF_C1I + idx] = (float)(2.0 * (c1r * ri + c1i * rr));
}

// Per-h scan matrices: V2 (states x j), T (t x j Toeplitz, D on diag), CW (t x carry-state).
__global__ void setup_scan_mats(const float* __restrict__ P,
                                const float* __restrict__ Dp,
                                u16* __restrict__ PM) {
    const int h = blockIdx.x;
    const int t = threadIdx.x;   // 0..63
    __shared__ float Wr[65][17], Wi[65][17];
    __shared__ float KF[64], KB[64];
    __shared__ float c0r[16], c0i[16], c1r[16], c1i[16];
    if (t < 16) {
        c0r[t] = P[OFF_C0R + h * NN + t]; c0i[t] = P[OFF_C0I + h * NN + t];
        c1r[t] = P[OFF_C1R + h * NN + t]; c1i[t] = P[OFF_C1I + h * NN + t];
        double wr = (double)P[OFF_WR + h * NN + t], wi = (double)P[OFF_WI + h * NN + t];
        double pr = 1.0, pi = 0.0;
        for (int tau = 0; tau <= 64; ++tau) {
            Wr[tau][t] = (float)pr; Wi[tau][t] = (float)pi;
            double nr = pr * wr - pi * wi, ni = pr * wi + pi * wr;
            pr = nr; pi = ni;
        }
    }
    __syncthreads();
    {
        float kf = 0.f, kb = 0.f;
        #pragma unroll
        for (int n = 0; n < 16; ++n) {
            kf = fmaf(c0r[n], Wr[t][n], fmaf(-c0i[n], Wi[t][n], kf));
            kb = fmaf(c1r[n], Wr[t][n], fmaf(-c1i[n], Wi[t][n], kb));
        }
        KF[t] = kf; KB[t] = kb;
    }
    __syncthreads();
    u16* base = PM + (size_t)h * PM_STRIDE;
    {
        int n = (t & 31) >> 1, reim = t & 1;
        bool fwd = t < 32;
        for (int j = 0; j < 64; ++j) {
            int e = fwd ? (63 - j) : j;
            float v = reim ? Wi[e][n] : Wr[e][n];
            __hip_bfloat16 hb = f2b(v);
            base[PM_V2H + t * 64 + j] = *(u16*)&hb;
            base[PM_V2L + t * 64 + j] = f2us(v - b2f(hb));
        }
    }
    {
        float Dh = Dp[h];
        for (int j = 0; j < 64; ++j) {
            float v = (j < t) ? KF[t - j] : ((j == t) ? (KF[0] + Dh) : KB[j - t - 1]);
            __hip_bfloat16 hb = f2b(v);
            base[PM_TH + t * 64 + j] = *(u16*)&hb;
            base[PM_TL + t * 64 + j] = f2us(v - b2f(hb));
        }
    }
    {
        #pragma unroll
        for (int n = 0; n < 16; ++n) {
            float Rw = Wr[t + 1][n], Iw = Wi[t + 1][n];
            float af = fmaf(c0r[n], Rw, -c0i[n] * Iw);
            float bf = -fmaf(c0r[n], Iw, c0i[n] * Rw);
            float Rb = Wr[63 - t][n], Ib = Wi[63 - t][n];
            float ab = fmaf(c1r[n], Rb, -c1i[n] * Ib);
            float bb = -fmaf(c1r[n], Ib, c1i[n] * Rb);
            float vals[4] = {af, bf, ab, bb};
            int cols[4] = {2 * n, 2 * n + 1, 32 + 2 * n, 32 + 2 * n + 1};
            #pragma unroll
            for (int q = 0; q < 4; ++q) {
                __hip_bfloat16 hb = f2b(vals[q]);
                base[PM_CWH + t * 64 + cols[q]] = *(u16*)&hb;
                base[PM_CWL + t * 64 + cols[q]] = f2us(vals[q] - b2f(hb));
            }
        }
    }
}

__global__ void part_t_kernel(const float* __restrict__ emb,
                              const float* __restrict__ w,
                              const float* __restrict__ bias,
                              float* __restrict__ P) {
    int idx = blockIdx.x * blockDim.x + threadIdx.x;
    if (idx >= BB * HH) return;
    int b = idx / HH, h = idx % HH;
    float s = bias[h];
    const float* er = emb + (size_t)b * DTE;
    const float* wr = w + (size_t)h * DTE;
    for (int e = 0; e < DTE; ++e) s = fmaf(er[e], wr[e], s);
    P[OFF_PT + idx] = s;
}

// split fp32 -> bf16 hi + bf16 lo (residual)
__global__ void convert_w_split(const float* __restrict__ src,
                                u16* __restrict__ hi, u16* __restrict__ lo, int n) {
    int i = blockIdx.x * 256 + threadIdx.x;
    if (i < n) {
        float v = src[i];
        __hip_bfloat16 hb = f2b(v);
        hi[i] = *reinterpret_cast<u16*>(&hb);
        lo[i] = f2us(v - b2f(hb));
    }
}

// Convert weight matrix (rows x Ktot fp32) into MFMA A-fragment order.
// Block b = mi*KS + ks; lane holds row mi*16+(lane&15), k = ks*32+(lane>>4)*8 .. +8.
__global__ void convert_w_frag(const float* __restrict__ src, u16* __restrict__ dst,
                               int KS, int Ktot) {
    int b = blockIdx.x;
    int lane = threadIdx.x;
    int mi = b / KS, ks = b % KS;
    int row = mi * 16 + (lane & 15);
    int col = ks * 32 + (lane >> 4) * 8;
    const float* s = src + (size_t)row * Ktot + col;
    u16 pk[8];
    #pragma unroll
    for (int j = 0; j < 8; ++j) pk[j] = f2us(s[j]);
    *(int4*)&dst[((size_t)b * 64 + lane) * 8] = *(const int4*)pk;
}

__global__ void tln_kernel(const float* __restrict__ in, float* __restrict__ out,
                           const float* __restrict__ mptr, const float* __restrict__ sptr,
                           const float* __restrict__ part_t) {
    int b = blockIdx.y;
    int l0 = blockIdx.x * 64;
    int t = threadIdx.x;
    int q = t >> 6, li = t & 63;
    const float* base = in + (size_t)b * HH * LL + l0 + li;
    float sum = 0.f, sq = 0.f;
    for (int i = 0; i < 64; ++i) {
        float v = base[(size_t)(q * 64 + i) * LL];
        sum += v; sq = fmaf(v, v, sq);
    }
    __shared__ float rs[4][64], rq[4][64], meanS[64], scaleS[64];
    rs[q][li] = sum; rq[q][li] = sq;
    __syncthreads();
    if (q == 0) {
        float s  = rs[0][li] + rs[1][li] + rs[2][li] + rs[3][li];
        float s2 = rq[0][li] + rq[1][li] + rq[2][li] + rq[3][li];
        float mean = s * (1.f / 256.f);
        float var  = fmaxf(s2 * (1.f / 256.f) - mean * mean, 0.f);
        meanS[li]  = mean;
        scaleS[li] = sptr[0] / sqrtf(var);
    }
    __syncthreads();
    float mean = meanS[li], scale = scaleS[li], m = mptr[0];
    float* ob = out + (size_t)b * HH * LL + l0 + li;
    for (int i = 0; i < 64; ++i) {
        int h = q * 64 + i;
        float v = base[(size_t)h * LL];
        float y = scale * (v - mean + m) + part_t[b * HH + h];
        ob[(size_t)h * LL] = y;
    }
}

__global__ void tln2t_kernel(const float* __restrict__ in, u16* __restrict__ outT,
                             const float* __restrict__ mptr, const float* __restrict__ sptr) {
    int b = blockIdx.y;
    int l0 = blockIdx.x * 64;
    int t = threadIdx.x;
    int q = t >> 6, li = t & 63;
    const float* base = in + (size_t)b * HH * LL + l0 + li;
    float sum = 0.f, sq = 0.f;
    for (int i = 0; i < 64; ++i) {
        float v = base[(size_t)(q * 64 + i) * LL];
        sum += v; sq = fmaf(v, v, sq);
    }
    __shared__ float rs[4][64], rq[4][64], meanS[64], scaleS[64];
    __shared__ u16 TT[64 * 262];
    rs[q][li] = sum; rq[q][li] = sq;
    __syncthreads();
    if (q == 0) {
        float s  = rs[0][li] + rs[1][li] + rs[2][li] + rs[3][li];
        float s2 = rq[0][li] + rq[1][li] + rq[2][li] + rq[3][li];
        float mean = s * (1.f / 256.f);
        float var  = fmaxf(s2 * (1.f / 256.f) - mean * mean, 0.f);
        meanS[li]  = mean;
        scaleS[li] = sptr[0] / sqrtf(var);
    }
    __syncthreads();
    float mean = meanS[li], scale = scaleS[li], m = mptr[0];
    for (int i = 0; i < 64; ++i) {
        int h = q * 64 + i;
        float v = base[(size_t)h * LL];
        TT[li * 262 + h] = f2us(scale * (v - mean + m));
    }
    __syncthreads();
    #pragma unroll
    for (int i = 0; i < 32; ++i) {
        int idx = t + i * 256;
        int c = idx & 127, l = idx >> 7;
        unsigned int v = *(const unsigned int*)&TT[l * 262 + 2 * c];
        *(unsigned int*)&outT[((size_t)b * LL + l0 + l) * 256 + 2 * c] = v;
    }
}

// ---- MFMA scan (unchanged; verified)
constexpr int UPAD = 136;
constexpr int SPAD = 72;

__global__ __launch_bounds__(256, 3) void scan_mfma(
    const float* __restrict__ uIn, const float* __restrict__ P,
    const u16* __restrict__ PM, float* __restrict__ ys)
{
    __shared__ __align__(16) u16 U[128 * UPAD];
    __shared__ __align__(16) u16 SES[128 * SPAD];

    const int bh  = blockIdx.x;
    const int h   = bh & (HH - 1);
    const int tid = threadIdx.x;
    const int lane = tid & 63;
    const int wq   = tid >> 6;
    const u16* pm = PM + (size_t)h * PM_STRIDE;
    const float* urow = uIn + (size_t)bh * LL;
    float* yrow = ys + (size_t)bh * LL;

    {
        const float4* u4 = (const float4*)urow;
        #pragma unroll
        for (int i = 0; i < 8; ++i) {
            int e4 = tid + i * 256;
            float4 v = u4[e4];
            int g = e4 << 2, c = g >> 6, j = g & 63;
            u16 hi4[4], lo4[4];
            #pragma unroll
            for (int q = 0; q < 4; ++q) {
                float f = (&v.x)[q];
                __hip_bfloat16 hb = f2b(f);
                hi4[q] = *(u16*)&hb;
                lo4[q] = f2us(f - b2f(hb));
            }
            *(ushort4*)&U[c * UPAD + j]      = *(ushort4*)hi4;
            *(ushort4*)&U[c * UPAD + 64 + j] = *(ushort4*)lo4;
        }
    }
    __syncthreads();

    const int cb    = wq * 32 + (lane & 15);
    const int kfrag = ((lane >> 4) & 3) * 8;
    const int arow_lo = lane & 15;

    bx8 ubh[2][2], ubl[2][2];
    #pragma unroll
    for (int nt = 0; nt < 2; ++nt) {
        int c = cb + nt * 16;
        #pragma unroll
        for (int ks = 0; ks < 2; ++ks) {
            ubh[nt][ks] = *(const bx8*)&U[c * UPAD + ks * 32 + kfrag];
            ubl[nt][ks] = *(const bx8*)&U[c * UPAD + 64 + ks * 32 + kfrag];
        }
    }

    {
        fx4 acc[4][2];
        #pragma unroll
        for (int mt = 0; mt < 4; ++mt)
            #pragma unroll
            for (int nt = 0; nt < 2; ++nt) { fx4 z = {0.f,0.f,0.f,0.f}; acc[mt][nt] = z; }
        #pragma unroll
        for (int mt = 0; mt < 4; ++mt) {
            #pragma unroll
            for (int ks = 0; ks < 2; ++ks) {
                int ao = (mt * 16 + arow_lo) * 64 + ks * 32 + kfrag;
                bx8 vh = *(const bx8*)&pm[PM_V2H + ao];
                bx8 vl = *(const bx8*)&pm[PM_V2L + ao];
                #pragma unroll
                for (int nt = 0; nt < 2; ++nt) {
                    acc[mt][nt] = __builtin_amdgcn_mfma_f32_16x16x32_bf16(vh, ubh[nt][ks], acc[mt][nt], 0, 0, 0);
                    acc[mt][nt] = __builtin_amdgcn_mfma_f32_16x16x32_bf16(vh, ubl[nt][ks], acc[mt][nt], 0, 0, 0);
                    acc[mt][nt] = __builtin_amdgcn_mfma_f32_16x16x32_bf16(vl, ubh[nt][ks], acc[mt][nt], 0, 0, 0);
                }
            }
        }
        #pragma unroll
        for (int mt = 0; mt < 4; ++mt)
            #pragma unroll
            for (int nt = 0; nt < 2; ++nt) {
                int c = cb + nt * 16;
                int row = mt * 16 + (lane >> 4) * 4;
                #pragma unroll
                for (int r = 0; r < 4; ++r)
                    SES[c * SPAD + row + r] = f2us(acc[mt][nt][r]);
            }
    }
    __syncthreads();

    if (tid < 32) {
        const int d3 = tid >> 4, n = tid & 15;
        float wSr = P[OFF_WSR + h * NN + n], wSi = P[OFF_WSI + h * NN + n];
        const int kk = d3 * 32 + 2 * n;
        float cr = 0.f, ci = 0.f;
        if (d3 == 0) {
            for (int q = 0; q < CHN; ++q) {
                unsigned* p = (unsigned*)&SES[q * SPAD + kk];
                unsigned pv = *p;
                float fr = lo2f(pv), fi = hi2f(pv);
                *p = pack2(cr, ci);
                float nr2 = fmaf(wSr, cr, fmaf(-wSi, ci, fr));
                float ni2 = fmaf(wSr, ci, fmaf(wSi, cr, fi));
                cr = nr2; ci = ni2;
            }
        } else {
            for (int q = CHN - 1; q >= 0; --q) {
                unsigned* p = (unsigned*)&SES[q * SPAD + kk];
                unsigned pv = *p;
                float fr = lo2f(pv), fi = hi2f(pv);
                *p = pack2(cr, ci);
                float nr2 = fmaf(wSr, cr, fmaf(-wSi, ci, fr));
                float ni2 = fmaf(wSr, ci, fmaf(wSi, cr, fi));
                cr = nr2; ci = ni2;
            }
        }
    }
    __syncthreads();

    {
        bx8 sb[2][2];
        #pragma unroll
        for (int nt = 0; nt < 2; ++nt) {
            int c = cb + nt * 16;
            #pragma unroll
            for (int ks = 0; ks < 2; ++ks)
                sb[nt][ks] = *(const bx8*)&SES[c * SPAD + ks * 32 + kfrag];
        }
        fx4 acc[4][2];
        #pragma unroll
        for (int mt = 0; mt < 4; ++mt)
            #pragma unroll
            for (int nt = 0; nt < 2; ++nt) { fx4 z = {0.f,0.f,0.f,0.f}; acc[mt][nt] = z; }
        #pragma unroll
        for (int mt = 0; mt < 4; ++mt) {
            #pragma unroll
            for (int ks = 0; ks < 2; ++ks) {
                int ao = (mt * 16 + arow_lo) * 64 + ks * 32 + kfrag;
                bx8 th = *(const bx8*)&pm[PM_TH + ao];
                bx8 tl = *(const bx8*)&pm[PM_TL + ao];
                bx8 ch = *(const bx8*)&pm[PM_CWH + ao];
                bx8 cl = *(const bx8*)&pm[PM_CWL + ao];
                #pragma unroll
                for (int nt = 0; nt < 2; ++nt) {
                    acc[mt][nt] = __builtin_amdgcn_mfma_f32_16x16x32_bf16(th, ubh[nt][ks], acc[mt][nt], 0, 0, 0);
                    acc[mt][nt] = __builtin_amdgcn_mfma_f32_16x16x32_bf16(th, ubl[nt][ks], acc[mt][nt], 0, 0, 0);
                    acc[mt][nt] = __builtin_amdgcn_mfma_f32_16x16x32_bf16(tl, ubh[nt][ks], acc[mt][nt], 0, 0, 0);
                    acc[mt][nt] = __builtin_amdgcn_mfma_f32_16x16x32_bf16(ch, sb[nt][ks], acc[mt][nt], 0, 0, 0);
                    acc[mt][nt] = __builtin_amdgcn_mfma_f32_16x16x32_bf16(cl, sb[nt][ks], acc[mt][nt], 0, 0, 0);
                }
            }
        }
        #pragma unroll
        for (int mt = 0; mt < 4; ++mt)
            #pragma unroll
            for (int nt = 0; nt < 2; ++nt) {
                int c = cb + nt * 16;
                float4 ov;
                #pragma unroll
                for (int r = 0; r < 4; ++r)
                    (&ov.x)[r] = gelu_tanh(acc[mt][nt][r]);
                *(float4*)&yrow[c * 64 + mt * 16 + (lane >> 4) * 4] = ov;
            }
    }
}

// ---- GLU output projection via split-bf16 MFMA (R2 version, verified 97 us).
__global__ __launch_bounds__(256, 2) void gemm_glu_mfma(
    const u16* __restrict__ Whi, const u16* __restrict__ Wlo,
    const float* __restrict__ Y, const float* __restrict__ bias,
    const float* __restrict__ xres, float* __restrict__ out)
{
    __shared__ __align__(16) char smem[65536];
    u16* Ah = (u16*)smem;
    u16* Al = Ah + 8192;
    u16* Bh = Al + 8192;
    u16* Bl = Bh + 8192;

    const int tid  = threadIdx.x;
    const int lane = tid & 63;
    const int wv   = tid >> 6;
    const int wrh  = wv & 1;
    const int wch  = wv >> 1;
    const int bz   = blockIdx.z;
    const int l0   = blockIdx.x * 128;
    const int c0   = blockIdx.y * 64;

    fx4 acc[4][4];
    #pragma unroll
    for (int i = 0; i < 4; ++i)
        #pragma unroll
        for (int j = 0; j < 4; ++j) {
            fx4 z = {0.f, 0.f, 0.f, 0.f};
            acc[i][j] = z;
        }

    const int am  = tid & 127;
    const int akh = tid >> 7;
    const int aorow = (am < 64) ? (c0 + am) : (c0 + 256 + (am - 64));
    const int amt = am >> 4, amm = am & 15;

    const int bli = (tid & 63) + ((tid >> 6) & 1) * 64;
    const int bkh = tid >> 7;
    const int bnt = bli >> 4, bcol = bli & 15;

    const float* Yb = Y + (size_t)bz * HH * LL + l0;

    for (int k0 = 0; k0 < 256; k0 += 64) {
        #pragma unroll
        for (int oct = 0; oct < 4; ++oct) {
            int k = k0 + akh * 32 + oct * 8;
            int4 vh = *(const int4*)&Whi[(size_t)aorow * 256 + k];
            int4 vl = *(const int4*)&Wlo[(size_t)aorow * 256 + k];
            int base = ((akh * 8 + amt) * 64 + amm + (oct << 4)) * 8;
            *(int4*)&Ah[base] = vh;
            *(int4*)&Al[base] = vl;
        }
        #pragma unroll
        for (int oct = 0; oct < 4; ++oct) {
            int kb = k0 + bkh * 32 + oct * 8;
            float v[8];
            #pragma unroll
            for (int j = 0; j < 8; ++j)
                v[j] = Yb[(size_t)(kb + j) * LL + bli];
            u16 h8[8], l8[8];
            #pragma unroll
            for (int j = 0; j < 8; ++j) {
                __hip_bfloat16 hb = f2b(v[j]);
                h8[j] = *reinterpret_cast<u16*>(&hb);
                l8[j] = f2us(v[j] - b2f(hb));
            }
            int base = ((bkh * 8 + bnt) * 64 + bcol + (oct << 4)) * 8;
            *(int4*)&Bh[base] = *(const int4*)h8;
            *(int4*)&Bl[base] = *(const int4*)l8;
        }
        __syncthreads();
        #pragma unroll
        for (int ks = 0; ks < 2; ++ks) {
            bx8 bh[4], bl[4];
            #pragma unroll
            for (int nt = 0; nt < 4; ++nt) {
                int base = ((ks * 8 + wch * 4 + nt) * 64 + lane) * 8;
                bh[nt] = *(const bx8*)&Bh[base];
                bl[nt] = *(const bx8*)&Bl[base];
            }
            #pragma unroll
            for (int mt = 0; mt < 4; ++mt) {
                int base = ((ks * 8 + wrh * 4 + mt) * 64 + lane) * 8;
                bx8 ah = *(const bx8*)&Ah[base];
                bx8 al = *(const bx8*)&Al[base];
                #pragma unroll
                for (int nt = 0; nt < 4; ++nt) {
                    acc[mt][nt] = __builtin_amdgcn_mfma_f32_16x16x32_bf16(ah, bh[nt], acc[mt][nt], 0, 0, 0);
                    acc[mt][nt] = __builtin_amdgcn_mfma_f32_16x16x32_bf16(ah, bl[nt], acc[mt][nt], 0, 0, 0);
                    acc[mt][nt] = __builtin_amdgcn_mfma_f32_16x16x32_bf16(al, bh[nt], acc[mt][nt], 0, 0, 0);
                }
            }
        }
        __syncthreads();
    }

    float* zbuf = (float*)smem;
    if (wrh == 1) {
        #pragma unroll
        for (int mt = 0; mt < 4; ++mt) {
            int mloc = mt * 16 + (lane >> 4) * 4;
            float b1v[4];
            #pragma unroll
            for (int r = 0; r < 4; ++r) b1v[r] = bias[c0 + 256 + mloc + r];
            #pragma unroll
            for (int nt = 0; nt < 4; ++nt) {
                int nloc = nt * 16 + (lane & 15);
                #pragma unroll
                for (int r = 0; r < 4; ++r)
                    zbuf[wch * 4160 + (mloc + r) * 65 + nloc] = acc[mt][nt][r] + b1v[r];
            }
        }
    }
    __syncthreads();
    if (wrh == 0) {
        #pragma unroll
        for (int mt = 0; mt < 4; ++mt) {
            int mloc = mt * 16 + (lane >> 4) * 4;
            float b0v[4];
            #pragma unroll
            for (int r = 0; r < 4; ++r) b0v[r] = bias[c0 + mloc + r];
            #pragma unroll
            for (int nt = 0; nt < 4; ++nt) {
                int nloc = nt * 16 + (lane & 15);
                int l = l0 + wch * 64 + nloc;
                #pragma unroll
                for (int r = 0; r < 4; ++r) {
                    float z1 = zbuf[wch * 4160 + (mloc + r) * 65 + nloc];
                    float z0 = acc[mt][nt][r] + b0v[r];
                    size_t ga = ((size_t)bz * HH + c0 + mloc + r) * LL + l;
                    out[ga] = z0 * sigmoid_(z1) + xres[ga];
                }
            }
        }
    }
}

// ---- Fused FF: out += resid; one 64-l tile per block; hidden kept in LDS.
// FF1: H = gelu(W1 @ X + b1) per 128-hidden chunk; FF2: acc += W2chunk @ H.
// Weights pre-converted to fragment order (direct coalesced 16B/lane loads, L2-hot).
__global__ __launch_bounds__(256, 3) void ff_fused(
    const u16* __restrict__ W1f, const u16* __restrict__ W2f,
    const u16* __restrict__ Xt,
    const float* __restrict__ b1, const float* __restrict__ b2,
    float* __restrict__ io)
{
    __shared__ __align__(16) u16 Xf[64 * 256];   // 32 KB, frag-ordered X tile
    __shared__ __align__(16) u16 Hf[8192];       // 16 KB, frag-ordered H chunk

    const int tid  = threadIdx.x;
    const int lane = tid & 63;
    const int w    = tid >> 6;
    const int lq   = lane >> 4;
    const int l15  = lane & 15;
    const int bz   = blockIdx.y;
    const int l0   = blockIdx.x * 64;

    // stage X tile (t2T rows l0..l0+63, 256 ch) into fragment order
    {
        const int li = tid >> 2;
        const int cq = (tid & 3) * 64;
        const u16* srcp = Xt + ((size_t)bz * LL + l0 + li) * 256 + cq;
        const int nt = li >> 4, ll = li & 15;
        #pragma unroll
        for (int i = 0; i < 8; ++i) {
            int c = cq + i * 8;
            int4 v = *(const int4*)(srcp + i * 8);
            int addr = ((nt * 8 + (c >> 5)) * 64 + ((c >> 3) & 3) * 16 + ll) * 8;
            *(int4*)&Xf[addr] = v;
        }
    }
    __syncthreads();

    fx4 acc2[4][4];
    #pragma unroll
    for (int i = 0; i < 4; ++i)
        #pragma unroll
        for (int j = 0; j < 4; ++j) {
            fx4 z = {0.f, 0.f, 0.f, 0.f};
            acc2[i][j] = z;
        }

    #pragma unroll 1
    for (int hc = 0; hc < 4; ++hc) {
        // FF1: wave w computes hidden rows [hc*128 + w*32, +32)
        fx4 acc1[2][4];
        #pragma unroll
        for (int i = 0; i < 2; ++i)
            #pragma unroll
            for (int j = 0; j < 4; ++j) {
                fx4 z = {0.f, 0.f, 0.f, 0.f};
                acc1[i][j] = z;
            }
        #pragma unroll
        for (int ks = 0; ks < 8; ++ks) {
            bx8 xb[4];
            #pragma unroll
            for (int nt = 0; nt < 4; ++nt)
                xb[nt] = *(const bx8*)&Xf[((nt * 8 + ks) * 64 + lane) * 8];
            #pragma unroll
            for (int mt = 0; mt < 2; ++mt) {
                int mi = hc * 8 + w * 2 + mt;
                bx8 a = *(const bx8*)&W1f[((size_t)(mi * 8 + ks) * 64 + lane) * 8];
                #pragma unroll
                for (int nt = 0; nt < 4; ++nt)
                    acc1[mt][nt] = __builtin_amdgcn_mfma_f32_16x16x32_bf16(a, xb[nt], acc1[mt][nt], 0, 0, 0);
            }
        }
        __syncthreads();   // prior FF2 reads of Hf complete
        // H = gelu(acc1 + b1) -> Hf in B-fragment order (one ds_write_b64 per frag)
        #pragma unroll
        for (int mt = 0; mt < 2; ++mt) {
            int hbase = hc * 128 + w * 32 + mt * 16 + lq * 4;
            float bb[4];
            #pragma unroll
            for (int r = 0; r < 4; ++r) bb[r] = b1[hbase + r];
            #pragma unroll
            for (int nt = 0; nt < 4; ++nt) {
                u16 pk[4];
                #pragma unroll
                for (int r = 0; r < 4; ++r)
                    pk[r] = f2us(gelu_tanh(acc1[mt][nt][r] + bb[r]));
                int addr = ((nt * 4 + w) * 64 + (mt * 2 + (lq >> 1)) * 16 + l15) * 8 + (lq & 1) * 4;
                *(ushort4*)&Hf[addr] = *(const ushort4*)pk;
            }
        }
        __syncthreads();
        // FF2: wave w accumulates out rows [w*64, +64) over K=128
        #pragma unroll
        for (int ks = 0; ks < 4; ++ks) {
            bx8 hb[4];
            #pragma unroll
            for (int nt = 0; nt < 4; ++nt)
                hb[nt] = *(const bx8*)&Hf[((nt * 4 + ks) * 64 + lane) * 8];
            #pragma unroll
            for (int mt2 = 0; mt2 < 4; ++mt2) {
                int mi2 = w * 4 + mt2, kk = hc * 4 + ks;
                bx8 a = *(const bx8*)&W2f[((size_t)(mi2 * 16 + kk) * 64 + lane) * 8];
                #pragma unroll
                for (int nt = 0; nt < 4; ++nt)
                    acc2[mt2][nt] = __builtin_amdgcn_mfma_f32_16x16x32_bf16(a, hb[nt], acc2[mt2][nt], 0, 0, 0);
            }
        }
    }

    // epilogue: += b2 + residual, in place
    #pragma unroll
    for (int mt2 = 0; mt2 < 4; ++mt2) {
        int m = w * 64 + mt2 * 16 + lq * 4;
        float b2v[4];
        #pragma unroll
        for (int r = 0; r < 4; ++r) b2v[r] = b2[m + r];
        #pragma unroll
        for (int nt = 0; nt < 4; ++nt) {
            int n = l0 + nt * 16 + l15;
            #pragma unroll
            for (int r = 0; r < 4; ++r) {
                size_t ga = ((size_t)bz * HH + m + r) * LL + n;
                io[ga] = acc2[mt2][nt][r] + b2v[r] + io[ga];
            }
        }
    }
}

extern "C" void kernel_launch(void* const* d_in, const int* in_sizes, int n_in,
                              void* d_out, int out_size, void* d_ws, size_t ws_size,
                              hipStream_t stream) {
    (void)in_sizes; (void)n_in; (void)out_size; (void)ws_size;
    const float* x      = (const float*)d_in[0];
    const float* emb    = (const float*)d_in[1];
    const float* fc_t_w = (const float*)d_in[2];
    const float* fc_t_b = (const float*)d_in[3];
    const float* log_dt = (const float*)d_in[4];
    const float* A_re   = (const float*)d_in[5];
    const float* A_im   = (const float*)d_in[6];
    const float* C_re   = (const float*)d_in[7];
    const float* C_im   = (const float*)d_in[8];
    const float* Dp     = (const float*)d_in[9];
    const float* out_w  = (const float*)d_in[10];
    const float* out_b  = (const float*)d_in[11];
    const float* n1_m   = (const float*)d_in[12];
    const float* n1_s   = (const float*)d_in[13];
    const float* n2_m   = (const float*)d_in[14];
    const float* n2_s   = (const float*)d_in[15];
    const float* ff_w1  = (const float*)d_in[16];
    const float* ff_b1  = (const float*)d_in[17];
    const float* ff_w2  = (const float*)d_in[18];
    const float* ff_b2  = (const float*)d_in[19];
    float* outp = (float*)d_out;

    // Workspace map (floats, total 2*BHL = 128 MiB):
    //   region A [0, BHL):              u fp32 -> ys4 (scan in place) -> t2T bf16
    //   PM at 1.5*BHL (12MB)
    //   WP corner [2*BHL-512K floats):  bf16 weights + P
    float* wsf  = (float*)d_ws;
    float* u    = wsf;
    u16*   t2T  = (u16*)wsf;
    u16*   PM   = (u16*)(wsf + BHL + BHL / 2);      // 256*24576 u16 = 12 MB
    constexpr size_t WPOFF = 2 * BHL - 524288;
    u16*   W1f  = (u16*)(wsf + WPOFF);              // 512*256 bf16 frag-ordered
    u16*   W2f  = W1f + 131072;                     // 256*512 bf16 frag-ordered
    u16*   WOh  = W2f + 131072;                     // out_w hi 512*256 bf16
    u16*   WOl  = WOh + 131072;                     // out_w lo 512*256 bf16
    float* P    = wsf + WPOFF + 262144;             // 34,816 floats

    setup_s4_params<<<16, 256, 0, stream>>>(log_dt, A_re, A_im, C_re, C_im, P);
    part_t_kernel<<<8, 256, 0, stream>>>(emb, fc_t_w, fc_t_b, P);
    setup_scan_mats<<<HH, 64, 0, stream>>>(P, Dp, PM);
    convert_w_frag<<<256, 64, 0, stream>>>(ff_w1, W1f, 8, 256);    // 32 mi x 8 ks
    convert_w_frag<<<256, 64, 0, stream>>>(ff_w2, W2f, 16, 512);   // 16 mi x 16 ks
    convert_w_split<<<512, 256, 0, stream>>>(out_w, WOh, WOl, 512 * 256);

    // u = TLN1(x) + part_t
    tln_kernel<<<dim3(LL / 64, BB), 256, 0, stream>>>(x, u, n1_m, n1_s, P + OFF_PT);

    // ys4 = gelu(S4_bidir(u) + u*D), in place over u  (MFMA formulation)
    scan_mfma<<<BB * HH, 256, 0, stream>>>(u, P, PM, u);

    // res = x + GLU(out_w @ ys4 + out_b) -> d_out
    gemm_glu_mfma<<<dim3(LL / 128, 4, BB), 256, 0, stream>>>(WOh, WOl, u, out_b, x, outp);

    // t2T = TLN2(res) transposed bf16
    tln2t_kernel<<<dim3(LL / 64, BB), 256, 0, stream>>>(outp, t2T, n2_m, n2_s);

    // Fused FF (both layers, hidden in LDS), += residual in place on d_out
    ff_fused<<<dim3(LL / 64, BB), 256, 0, stream>>>(W1f, W2f, t2T, ff_b1, ff_b2, outp);
}